// Round 1
// baseline (2486.744 us; speedup 1.0000x reference)
//
#include <hip/hip_runtime.h>

#define L_ 6
#define E_ 768
#define H_ 12
#define FF_ 3072
#define NBATCH 8
#define T_ 1024

typedef __attribute__((ext_vector_type(8))) short bh8;     // 8 bf16 (4 VGPRs)
typedef __attribute__((ext_vector_type(4))) float f32x4;

__device__ inline ushort f2bf(float f) {
  unsigned u = __builtin_bit_cast(unsigned, f);
  u += 0x7fffu + ((u >> 16) & 1u);           // RNE
  return (ushort)(u >> 16);
}

// ---------------- bias pack: bqkv[l][2304] = concat(bq,bk,bv) ----------------
__global__ __launch_bounds__(256) void pack_bias(const float* __restrict__ bq,
                                                 const float* __restrict__ bk,
                                                 const float* __restrict__ bv,
                                                 float* __restrict__ bqkv) {
  int idx = blockIdx.x * 256 + threadIdx.x;   // < 6*2304
  int l = idx / 2304, j = idx % 2304;
  float v = (j < 768) ? bq[l * 768 + j]
          : (j < 1536) ? bk[l * 768 + j - 768]
                       : bv[l * 768 + j - 1536];
  bqkv[idx] = v;
}

// ---------------- weight transpose f32[K][N] -> bf16[N][K] ----------------
__global__ __launch_bounds__(256) void transpose_w(const float* __restrict__ src,
                                                   ushort* __restrict__ dst,
                                                   int K, int Nn,
                                                   long sstride, long dstride) {
  src += (long)blockIdx.z * sstride;
  dst += (long)blockIdx.z * dstride;
  __shared__ float t[32][33];
  int tx = threadIdx.x & 31, ty = threadIdx.x >> 5;   // ty 0..7
  int kb = blockIdx.x * 32, nb = blockIdx.y * 32;
#pragma unroll
  for (int i = 0; i < 4; i++) {
    int kr = ty + i * 8;
    t[kr][tx] = src[(long)(kb + kr) * Nn + nb + tx];
  }
  __syncthreads();
#pragma unroll
  for (int i = 0; i < 4; i++) {
    int nr = ty + i * 8;
    dst[(long)(nb + nr) * K + kb + tx] = f2bf(t[tx][nr]);
  }
}

// ---------------- embed: out = concat(cls, x) + pos ----------------
__global__ __launch_bounds__(256) void embed_k(const float* __restrict__ x,
                                               const float* __restrict__ pos,
                                               const float* __restrict__ cls,
                                               float* __restrict__ res,
                                               ushort* __restrict__ xb) {
  int idx = blockIdx.x * 256 + threadIdx.x;   // < 8192*192
  int c4 = idx % 192;
  int row = idx / 192;
  int t = row & 1023, n = row >> 10;
  f32x4 pv = ((const f32x4*)pos)[t * 192 + c4];
  f32x4 xv;
  if (t == 0) xv = ((const f32x4*)cls)[c4];
  else        xv = ((const f32x4*)x)[(size_t)(n * 1023 + t - 1) * 192 + c4];
  f32x4 s = xv + pv;
  ((f32x4*)res)[idx] = s;
  ushort4 h;
  h.x = f2bf(s[0]); h.y = f2bf(s[1]); h.z = f2bf(s[2]); h.w = f2bf(s[3]);
  ((ushort4*)xb)[idx] = h;
}

// ---------------- GEMM: C[M][N] = A[M][K](bf16) * Bt[N][K](bf16) ----------------
// MODE 0: out16 = bf16(acc + bias)                (QKV)
// MODE 1: out32 = acc + bias + resid              (Wo / FF2, pre-LN)
// MODE 2: out16 = bf16(gelu(acc + bias))          (FF1)
template <int MODE>
__global__ __launch_bounds__(256) void gemm_bt(const ushort* __restrict__ A,
                                               const ushort* __restrict__ Bt,
                                               int M, int N, int K,
                                               const float* __restrict__ bias,
                                               const float* __restrict__ resid,
                                               float* __restrict__ out32,
                                               ushort* __restrict__ out16) {
  __shared__ ushort As[128 * 72];   // rows padded 64->72 elems (144B) : conflict-free b128 reads
  __shared__ ushort Bs[128 * 72];
  int tid = threadIdx.x;
  int wid = tid >> 6, lane = tid & 63;
  int wm = wid >> 1, wn = wid & 1;
  int l15 = lane & 15, lhi = lane >> 4;
  int row0 = blockIdx.x * 128, col0 = blockIdx.y * 128;

  f32x4 acc[4][4];
#pragma unroll
  for (int i = 0; i < 4; i++)
#pragma unroll
    for (int j = 0; j < 4; j++) acc[i][j] = (f32x4){0.f, 0.f, 0.f, 0.f};

  int sr = tid >> 3;          // 0..31
  int sc = (tid & 7) * 8;     // 0..56
  const ushort* Ap = A + (size_t)(row0 + sr) * K + sc;
  const ushort* Bp = Bt + (size_t)(col0 + sr) * K + sc;

  for (int k0 = 0; k0 < K; k0 += 64) {
    bh8 ra[4], rb[4];
#pragma unroll
    for (int p = 0; p < 4; p++) ra[p] = *(const bh8*)(Ap + (size_t)p * 32 * K + k0);
#pragma unroll
    for (int p = 0; p < 4; p++) rb[p] = *(const bh8*)(Bp + (size_t)p * 32 * K + k0);
    __syncthreads();
#pragma unroll
    for (int p = 0; p < 4; p++) *(bh8*)(As + (p * 32 + sr) * 72 + sc) = ra[p];
#pragma unroll
    for (int p = 0; p < 4; p++) *(bh8*)(Bs + (p * 32 + sr) * 72 + sc) = rb[p];
    __syncthreads();
#pragma unroll
    for (int ks = 0; ks < 2; ks++) {
      bh8 af[4], bfr[4];
#pragma unroll
      for (int i = 0; i < 4; i++)
        af[i] = *(const bh8*)(As + (wm * 64 + i * 16 + l15) * 72 + ks * 32 + lhi * 8);
#pragma unroll
      for (int j = 0; j < 4; j++)
        bfr[j] = *(const bh8*)(Bs + (wn * 64 + j * 16 + l15) * 72 + ks * 32 + lhi * 8);
#pragma unroll
      for (int i = 0; i < 4; i++)
#pragma unroll
        for (int j = 0; j < 4; j++)
          acc[i][j] = __builtin_amdgcn_mfma_f32_16x16x32_bf16(af[i], bfr[j], acc[i][j], 0, 0, 0);
    }
  }

#pragma unroll
  for (int j = 0; j < 4; j++) {
    int col = col0 + wn * 64 + j * 16 + l15;
    float bv = bias[col];
#pragma unroll
    for (int i = 0; i < 4; i++) {
      int rbase = row0 + wm * 64 + i * 16 + lhi * 4;
#pragma unroll
      for (int r = 0; r < 4; r++) {
        int row = rbase + r;
        size_t o = (size_t)row * N + col;
        float v = acc[i][j][r] + bv;
        if (MODE == 0) {
          out16[o] = f2bf(v);
        } else if (MODE == 1) {
          out32[o] = v + resid[o];
        } else {
          v = 0.5f * v * (1.f + erff(v * 0.70710678118f));
          out16[o] = f2bf(v);
        }
      }
    }
  }
}

// ---------------- flash attention: qkv bf16 [8192][2304] -> attb bf16 [8192][768] ----------------
__global__ __launch_bounds__(256) void attn_k(const ushort* __restrict__ qkv,
                                              const int* __restrict__ mask,
                                              ushort* __restrict__ attb) {
  int qt = blockIdx.x, h = blockIdx.y, n = blockIdx.z;
  int tid = threadIdx.x, wid = tid >> 6, lane = tid & 63;
  int l15 = lane & 15, lhi = lane >> 4;
  __shared__ ushort Ks[32 * 72];     // [kv][d] padded 64->72
  __shared__ ushort Vt[64 * 40];     // [d][kv] padded 32->40
  __shared__ ushort Pt[4 * 16 * 40]; // per-wave P tile [16][40]
  ushort* Pw = Pt + wid * 640;

  int q0 = qt * 64 + wid * 16;
  size_t rowQ = (size_t)(n * 1024 + q0 + l15) * 2304 + h * 64;
  bh8 qf0 = *(const bh8*)(qkv + rowQ + lhi * 8);
  bh8 qf1 = *(const bh8*)(qkv + rowQ + 32 + lhi * 8);

  f32x4 o[4];
#pragma unroll
  for (int i = 0; i < 4; i++) o[i] = (f32x4){0.f, 0.f, 0.f, 0.f};
  float m_[4], l_[4];
#pragma unroll
  for (int r = 0; r < 4; r++) { m_[r] = -3.0e38f; l_[r] = 0.f; }

  int skk = tid >> 3, sd0 = (tid & 7) * 8;

  for (int kb = 0; kb < 32; kb++) {
    int kv0 = kb * 32;
    __syncthreads();
    {
      size_t srow = (size_t)(n * 1024 + kv0 + skk) * 2304 + h * 64 + sd0;
      bh8 kvv = *(const bh8*)(qkv + srow + 768);
      *(bh8*)(Ks + skk * 72 + sd0) = kvv;
      bh8 vv = *(const bh8*)(qkv + srow + 1536);
#pragma unroll
      for (int i = 0; i < 8; i++) Vt[(sd0 + i) * 40 + skk] = (ushort)vv[i];
    }
    __syncthreads();

    f32x4 s0 = (f32x4){0.f, 0.f, 0.f, 0.f}, s1 = s0;
    s0 = __builtin_amdgcn_mfma_f32_16x16x32_bf16(qf0, *(const bh8*)(Ks + l15 * 72 + lhi * 8), s0, 0, 0, 0);
    s0 = __builtin_amdgcn_mfma_f32_16x16x32_bf16(qf1, *(const bh8*)(Ks + l15 * 72 + 32 + lhi * 8), s0, 0, 0, 0);
    s1 = __builtin_amdgcn_mfma_f32_16x16x32_bf16(qf0, *(const bh8*)(Ks + (16 + l15) * 72 + lhi * 8), s1, 0, 0, 0);
    s1 = __builtin_amdgcn_mfma_f32_16x16x32_bf16(qf1, *(const bh8*)(Ks + (16 + l15) * 72 + 32 + lhi * 8), s1, 0, 0, 0);

    int mk0 = mask[n * 1024 + kv0 + l15];
    int mk1 = mask[n * 1024 + kv0 + 16 + l15];
    float sv0[4], sv1[4], mt[4];
#pragma unroll
    for (int r = 0; r < 4; r++) {
      sv0[r] = (mk0 == 0 ? -1e20f : s0[r]) * 0.125f;
      sv1[r] = (mk1 == 0 ? -1e20f : s1[r]) * 0.125f;
      mt[r] = fmaxf(sv0[r], sv1[r]);
    }
#pragma unroll
    for (int off = 1; off < 16; off <<= 1)
#pragma unroll
      for (int r = 0; r < 4; r++) mt[r] = fmaxf(mt[r], __shfl_xor(mt[r], off, 64));
    float f[4];
#pragma unroll
    for (int r = 0; r < 4; r++) {
      float mn = fmaxf(m_[r], mt[r]);
      f[r] = __expf(m_[r] - mn);
      m_[r] = mn;
    }
    float p0[4], p1[4], ps[4];
#pragma unroll
    for (int r = 0; r < 4; r++) {
      p0[r] = __expf(sv0[r] - m_[r]);
      p1[r] = __expf(sv1[r] - m_[r]);
      ps[r] = p0[r] + p1[r];
    }
#pragma unroll
    for (int off = 1; off < 16; off <<= 1)
#pragma unroll
      for (int r = 0; r < 4; r++) ps[r] += __shfl_xor(ps[r], off, 64);
#pragma unroll
    for (int r = 0; r < 4; r++) l_[r] = l_[r] * f[r] + ps[r];
#pragma unroll
    for (int nb = 0; nb < 4; nb++)
#pragma unroll
      for (int r = 0; r < 4; r++) o[nb][r] *= f[r];

#pragma unroll
    for (int r = 0; r < 4; r++) {
      Pw[(lhi * 4 + r) * 40 + l15] = f2bf(p0[r]);
      Pw[(lhi * 4 + r) * 40 + 16 + l15] = f2bf(p1[r]);
    }
    bh8 pf = *(const bh8*)(Pw + l15 * 40 + lhi * 8);
#pragma unroll
    for (int nb = 0; nb < 4; nb++) {
      bh8 vf = *(const bh8*)(Vt + (nb * 16 + l15) * 40 + lhi * 8);
      o[nb] = __builtin_amdgcn_mfma_f32_16x16x32_bf16(pf, vf, o[nb], 0, 0, 0);
    }
  }

#pragma unroll
  for (int nb = 0; nb < 4; nb++)
#pragma unroll
    for (int r = 0; r < 4; r++) {
      float val = o[nb][r] / l_[r];
      int row = q0 + lhi * 4 + r;
      int col = h * 64 + nb * 16 + l15;
      attb[(size_t)(n * 1024 + row) * 768 + col] = f2bf(val);
    }
}

// ---------------- LayerNorm: y32 = LN(in)*g+b (f32), y16 = bf16(y32) ----------------
__global__ __launch_bounds__(256) void ln_k(const float* __restrict__ in,
                                            const float* __restrict__ g,
                                            const float* __restrict__ b,
                                            float* __restrict__ y32,
                                            ushort* __restrict__ y16) {
  int row = blockIdx.x, tid = threadIdx.x;
  size_t base = (size_t)row * 768;
  float v0 = in[base + tid], v1 = in[base + tid + 256], v2 = in[base + tid + 512];
  float s = v0 + v1 + v2;
  float sq = v0 * v0 + v1 * v1 + v2 * v2;
#pragma unroll
  for (int off = 32; off > 0; off >>= 1) {
    s += __shfl_down(s, off);
    sq += __shfl_down(sq, off);
  }
  __shared__ float sws[4], swq[4];
  int wid = tid >> 6, lane = tid & 63;
  if (lane == 0) { sws[wid] = s; swq[wid] = sq; }
  __syncthreads();
  float ts = sws[0] + sws[1] + sws[2] + sws[3];
  float tq = swq[0] + swq[1] + swq[2] + swq[3];
  float mean = ts * (1.f / 768.f);
  float var = tq * (1.f / 768.f) - mean * mean;
  float rstd = rsqrtf(var + 1e-5f);
#pragma unroll
  for (int i = 0; i < 3; i++) {
    int c = tid + i * 256;
    float vv = (i == 0) ? v0 : (i == 1) ? v1 : v2;
    float y = (vv - mean) * rstd * g[c] + b[c];
    y32[base + c] = y;
    y16[base + c] = f2bf(y);
  }
}

extern "C" void kernel_launch(void* const* d_in, const int* in_sizes, int n_in,
                              void* d_out, int out_size, void* d_ws, size_t ws_size,
                              hipStream_t stream) {
  const float* x    = (const float*)d_in[0];
  const int*   mask = (const int*)d_in[1];
  const float* pos  = (const float*)d_in[2];
  const float* cls  = (const float*)d_in[3];
  const float* Wq   = (const float*)d_in[4];
  const float* bq   = (const float*)d_in[5];
  const float* Wk   = (const float*)d_in[6];
  const float* bk   = (const float*)d_in[7];
  const float* Wv   = (const float*)d_in[8];
  const float* bv   = (const float*)d_in[9];
  const float* Wo   = (const float*)d_in[10];
  const float* bo   = (const float*)d_in[11];
  const float* ln1g = (const float*)d_in[12];
  const float* ln1b = (const float*)d_in[13];
  const float* ln2g = (const float*)d_in[14];
  const float* ln2b = (const float*)d_in[15];
  const float* Wf1  = (const float*)d_in[16];
  const float* bf1  = (const float*)d_in[17];
  const float* Wf2  = (const float*)d_in[18];
  const float* bf2  = (const float*)d_in[19];

  char* ws = (char*)d_ws;
  size_t off = 0;
  auto alloc = [&](size_t bytes) {
    char* p = ws + off;
    off += (bytes + 255) & ~(size_t)255;
    return p;
  };
  const size_t M = 8192;
  ushort* qkvt = (ushort*)alloc((size_t)L_ * 2304 * 768 * 2);
  ushort* wot  = (ushort*)alloc((size_t)L_ * 768 * 768 * 2);
  ushort* wf1t = (ushort*)alloc((size_t)L_ * 3072 * 768 * 2);
  ushort* wf2t = (ushort*)alloc((size_t)L_ * 768 * 3072 * 2);
  float*  bqkv = (float*)alloc((size_t)L_ * 2304 * 4);
  float*  res  = (float*)alloc(M * 768 * 4);
  float*  pre  = (float*)alloc(M * 768 * 4);
  ushort* xb   = (ushort*)alloc(M * 768 * 2);
  ushort* qkvb = (ushort*)alloc(M * 2304 * 2);
  ushort* attb = (ushort*)alloc(M * 768 * 2);
  ushort* ffb  = (ushort*)alloc(M * 3072 * 2);
  (void)ws_size; (void)in_sizes; (void)n_in; (void)out_size;

  dim3 tb(256);
  pack_bias<<<54, tb, 0, stream>>>(bq, bk, bv, bqkv);
  transpose_w<<<dim3(24, 24, 6), tb, 0, stream>>>(Wq, qkvt,              768, 768, 768L * 768, 2304L * 768);
  transpose_w<<<dim3(24, 24, 6), tb, 0, stream>>>(Wk, qkvt + 768 * 768,  768, 768, 768L * 768, 2304L * 768);
  transpose_w<<<dim3(24, 24, 6), tb, 0, stream>>>(Wv, qkvt + 2 * 768 * 768, 768, 768, 768L * 768, 2304L * 768);
  transpose_w<<<dim3(24, 24, 6), tb, 0, stream>>>(Wo, wot, 768, 768, 768L * 768, 768L * 768);
  transpose_w<<<dim3(24, 96, 6), tb, 0, stream>>>(Wf1, wf1t, 768, 3072, 768L * 3072, 3072L * 768);
  transpose_w<<<dim3(96, 24, 6), tb, 0, stream>>>(Wf2, wf2t, 3072, 768, 3072L * 768, 768L * 3072);
  embed_k<<<6144, tb, 0, stream>>>(x, pos, cls, res, xb);

  for (int l = 0; l < L_; l++) {
    gemm_bt<0><<<dim3(64, 18), tb, 0, stream>>>(xb, qkvt + (size_t)l * 2304 * 768,
                                                8192, 2304, 768, bqkv + l * 2304,
                                                nullptr, nullptr, qkvb);
    attn_k<<<dim3(16, 12, 8), tb, 0, stream>>>(qkvb, mask, attb);
    gemm_bt<1><<<dim3(64, 6), tb, 0, stream>>>(attb, wot + (size_t)l * 768 * 768,
                                               8192, 768, 768, bo + l * 768,
                                               res, pre, nullptr);
    ln_k<<<8192, tb, 0, stream>>>(pre, ln1g + l * 768, ln1b + l * 768, res, xb);
    gemm_bt<2><<<dim3(64, 24), tb, 0, stream>>>(xb, wf1t + (size_t)l * 3072 * 768,
                                                8192, 3072, 768, bf1 + l * 3072,
                                                nullptr, nullptr, ffb);
    gemm_bt<1><<<dim3(64, 6), tb, 0, stream>>>(ffb, wf2t + (size_t)l * 768 * 3072,
                                               8192, 768, 3072, bf2 + l * 768,
                                               res, pre, nullptr);
    float* y32 = (l == L_ - 1) ? (float*)d_out : res;
    ln_k<<<8192, tb, 0, stream>>>(pre, ln2g + l * 768, ln2b + l * 768, y32, xb);
  }
}